// Round 1
// baseline (3902.200 us; speedup 1.0000x reference)
//
#include <hip/hip_runtime.h>
#include <hip/hip_bf16.h>
#include <math.h>

// ---------------------------------------------------------------------------
// VaryMambaModel: batch=1, L=128
//   PRE_D=2048, D=4096, N=64, K=4, DI1=4096, DI2=8192, DTR1=128, DTR2=256
// Full f32 implementation (correctness-first baseline).
// ---------------------------------------------------------------------------

__device__ __forceinline__ float sigmoidf_(float x) {
  return 1.0f / (1.0f + __expf(-x));
}
__device__ __forceinline__ float softplusf_(float x) {
  // jax.nn.softplus = logaddexp(x, 0) = max(x,0) + log1p(exp(-|x|))
  return fmaxf(x, 0.0f) + log1pf(expf(-fabsf(x)));
}

// ---------------- prep: x0 = pe + cond*to_cond_w + to_cond_b ----------------
__global__ __launch_bounds__(256) void k_prep(const float* __restrict__ pe,
                                              const float* __restrict__ cw,
                                              const float* __restrict__ cb,
                                              const float* __restrict__ cond,
                                              float* __restrict__ x0) {
  int i = blockIdx.x * 256 + threadIdx.x;  // 128*2048
  int d = i & 2047;
  x0[i] = pe[i] + cond[0] * cw[d] + cb[d];
}

// ---------------- GEMM: P[s][m][n] = sum_{k in split s} X[m][k]*W[n][k] -----
// M == 128 always. Tile: 64 M x 128 N per block (256 threads), K chunk 64.
#define KC 64
#define MT 64
#define NT 128
__global__ __launch_bounds__(256) void k_gemm(const float* __restrict__ X, int ldx,
                                              const float* __restrict__ W, int ldw,
                                              float* __restrict__ P,
                                              int N, int K, int S) {
  __shared__ float Xs[KC][MT + 4];  // transposed: Xs[k][m]
  const int n0 = blockIdx.x * NT;
  const int m0 = blockIdx.y * MT;
  const int s  = blockIdx.z;
  const int Ks = K / S;       // multiple of KC by construction
  const int kbeg = s * Ks;
  const int t  = threadIdx.x;
  const int nl = t & 15;      // 16 n lanes
  const int mg = t >> 4;      // 16 m groups of 4

  float acc[4][8];
#pragma unroll
  for (int i = 0; i < 4; ++i)
#pragma unroll
    for (int j = 0; j < 8; ++j) acc[i][j] = 0.0f;

  const float* wp[8];
#pragma unroll
  for (int j = 0; j < 8; ++j)
    wp[j] = W + (size_t)(n0 + nl + 16 * j) * ldw + kbeg;

  for (int k0 = kbeg; k0 < kbeg + Ks; k0 += KC) {
    __syncthreads();
    // stage 64 rows(m) x 64 cols(k): 4096 elems, 16 per thread, coalesced in k
#pragma unroll
    for (int i = 0; i < 16; ++i) {
      int e = t + i * 256;
      int m = e >> 6;
      int kk = e & 63;
      Xs[kk][m] = X[(size_t)(m0 + m) * ldx + (k0 + kk)];
    }
    __syncthreads();
#pragma unroll
    for (int kk = 0; kk < KC; kk += 4) {
      float4 xv0 = *(const float4*)&Xs[kk + 0][mg * 4];
      float4 xv1 = *(const float4*)&Xs[kk + 1][mg * 4];
      float4 xv2 = *(const float4*)&Xs[kk + 2][mg * 4];
      float4 xv3 = *(const float4*)&Xs[kk + 3][mg * 4];
#pragma unroll
      for (int j = 0; j < 8; ++j) {
        const float4 wv = *(const float4*)(wp[j] + (k0 - kbeg) + kk);
        acc[0][j] += xv0.x * wv.x + xv1.x * wv.y + xv2.x * wv.z + xv3.x * wv.w;
        acc[1][j] += xv0.y * wv.x + xv1.y * wv.y + xv2.y * wv.z + xv3.y * wv.w;
        acc[2][j] += xv0.z * wv.x + xv1.z * wv.y + xv2.z * wv.z + xv3.z * wv.w;
        acc[3][j] += xv0.w * wv.x + xv1.w * wv.y + xv2.w * wv.z + xv3.w * wv.w;
      }
    }
  }

  float* Pd = P + (size_t)s * 128 * N;
#pragma unroll
  for (int i = 0; i < 4; ++i) {
    int m = m0 + mg * 4 + i;
#pragma unroll
    for (int j = 0; j < 8; ++j) {
      Pd[(size_t)m * N + (n0 + nl + 16 * j)] = acc[i][j];
    }
  }
}

// ---------------- reduce partials (+ optional softplus-bias epilogue) -------
__global__ __launch_bounds__(256) void k_reduce(const float* __restrict__ P,
                                                float* __restrict__ Y,
                                                int MN, int N, int S, int ep,
                                                const float* __restrict__ bias) {
  int i = (blockIdx.x * 256 + threadIdx.x) * 4;
  if (i >= MN) return;
  float4 v = *(const float4*)&P[i];
  for (int s = 1; s < S; ++s) {
    float4 p = *(const float4*)&P[(size_t)s * MN + i];
    v.x += p.x; v.y += p.y; v.z += p.z; v.w += p.w;
  }
  if (ep == 1) {
    int n = i % N;
    const float4 b = *(const float4*)&bias[n];
    v.x = softplusf_(v.x + b.x);
    v.y = softplusf_(v.y + b.y);
    v.z = softplusf_(v.z + b.z);
    v.w = softplusf_(v.w + b.w);
  }
  *(float4*)&Y[i] = v;
}

// ---------------- depthwise causal conv (K=4) + silu ------------------------
__global__ __launch_bounds__(256) void k_conv_silu(const float* __restrict__ xz,
                                                   const float* __restrict__ cw,
                                                   const float* __restrict__ cb,
                                                   float* __restrict__ xc, int DI) {
  int i = blockIdx.x * 256 + threadIdx.x;  // over 128*DI
  int l = i / DI;
  int d = i - l * DI;
  const float4 w = *(const float4*)&cw[d * 4];
  const float* xr = xz + d;  // column d of xz, row stride 2*DI
  int ld = 2 * DI;
  float s = cb[d];
  s += w.w * xr[l * ld];
  if (l >= 1) s += w.z * xr[(l - 1) * ld];
  if (l >= 2) s += w.y * xr[(l - 2) * ld];
  if (l >= 3) s += w.x * xr[(l - 3) * ld];
  xc[i] = s * sigmoidf_(s);
}

// ---------------- selective scan: wave per channel, lane = n ----------------
__global__ __launch_bounds__(256) void k_scan(const float* __restrict__ dt,
                                              const float* __restrict__ xz,
                                              const float* __restrict__ xc,
                                              const float* __restrict__ dbc,
                                              const float* __restrict__ A_log,
                                              const float* __restrict__ Dp,
                                              float* __restrict__ y,
                                              int DI, int DTR) {
  int d = blockIdx.x * 4 + (threadIdx.x >> 6);  // channel
  int lane = threadIdx.x & 63;                  // state index n
  float A = -__expf(A_log[d * 64 + lane]);
  float Dd = Dp[d];
  int ldbc = DTR + 128;
  const float* Bp = dbc + DTR + lane;
  const float* Cp = dbc + DTR + 64 + lane;
  float h = 0.0f;
  for (int l = 0; l < 128; ++l) {
    float dtv = dt[l * DI + d];
    float xcv = xc[l * DI + d];
    float zv  = xz[l * 2 * DI + DI + d];
    float Bv  = Bp[l * ldbc];
    float Cv  = Cp[l * ldbc];
    float dA  = __expf(dtv * A);
    h = dA * h + (dtv * Bv) * xcv;
    float c = h * Cv;
#pragma unroll
    for (int off = 32; off; off >>= 1) c += __shfl_xor(c, off, 64);
    if (lane == 0) y[l * DI + d] = (c + xcv * Dd) * (zv * sigmoidf_(zv));
  }
}

// ---------------------------------------------------------------------------
static inline void gemm(const float* X, int ldx, const float* W, int ldw,
                        float* dst, float* part, int N, int K, int S, int ep,
                        const float* bias, hipStream_t stream) {
  dim3 g(N / NT, 2, S);
  bool direct = (S == 1 && ep == 0);
  k_gemm<<<g, 256, 0, stream>>>(X, ldx, W, ldw, direct ? dst : part, N, K, S);
  if (!direct) {
    int MN = 128 * N;
    k_reduce<<<dim3(MN / 1024), 256, 0, stream>>>(part, dst, MN, N, S, ep, bias);
  }
}

extern "C" void kernel_launch(void* const* d_in, const int* in_sizes, int n_in,
                              void* d_out, int out_size, void* d_ws, size_t ws_size,
                              hipStream_t stream) {
  const float* pe        = (const float*)d_in[0];
  const float* to_cond_w = (const float*)d_in[1];
  const float* to_cond_b = (const float*)d_in[2];
  const float* condition = (const float*)d_in[3];
  // batch scalar: dict order puts it at [4]; be robust to signature order.
  const int o = (in_sizes[4] == 1) ? 5 : 4;
  const float* m1_in_proj  = (const float*)d_in[o + 0];
  const float* m1_conv_w   = (const float*)d_in[o + 1];
  const float* m1_conv_b   = (const float*)d_in[o + 2];
  const float* m1_x_proj   = (const float*)d_in[o + 3];
  const float* m1_dt_w     = (const float*)d_in[o + 4];
  const float* m1_dt_b     = (const float*)d_in[o + 5];
  const float* m1_A_log    = (const float*)d_in[o + 6];
  const float* m1_D        = (const float*)d_in[o + 7];
  const float* m1_out_proj = (const float*)d_in[o + 8];
  const float* m2_in_proj  = (const float*)d_in[o + 9];
  const float* m2_conv_w   = (const float*)d_in[o + 10];
  const float* m2_conv_b   = (const float*)d_in[o + 11];
  const float* m2_x_proj   = (const float*)d_in[o + 12];
  const float* m2_dt_w     = (const float*)d_in[o + 13];
  const float* m2_dt_b     = (const float*)d_in[o + 14];
  const float* m2_A_log    = (const float*)d_in[o + 15];
  const float* m2_D        = (const float*)d_in[o + 16];
  const float* m2_out_proj = (const float*)d_in[o + 17];

  float* ws   = (float*)d_ws;
  float* x0   = ws;             // 128*2048            = 262144
  float* mid  = ws + 262144;    // 128*2048            = 262144
  float* xz   = ws + 524288;    // 128*16384 (max)     = 2097152
  float* xc   = ws + 2621440;   // 128*8192  (max)     = 1048576
  float* dbc  = ws + 3670016;   // 128*384   (max)     = 49152
  float* dtb  = ws + 3719168;   // 128*8192  (max)     = 1048576
  float* yb   = ws + 4767744;   // 128*8192  (max)     = 1048576
  float* part = ws + 5816320;   // split-K partials    = 2097152 (8.4 MB)

  k_prep<<<1024, 256, 0, stream>>>(pe, to_cond_w, to_cond_b, condition, x0);

  // ---------------- mamba block 1: DI=4096, DTR=128 ----------------
  gemm(x0, 2048, m1_in_proj, 2048, xz, part, 8192, 2048, 2, 0, nullptr, stream);
  k_conv_silu<<<(128 * 4096) / 256, 256, 0, stream>>>(xz, m1_conv_w, m1_conv_b, xc, 4096);
  gemm(xc, 4096, m1_x_proj, 4096, dbc, part, 256, 4096, 64, 0, nullptr, stream);
  gemm(dbc, 256, m1_dt_w, 128, dtb, part, 4096, 128, 2, 1, m1_dt_b, stream);
  k_scan<<<1024, 256, 0, stream>>>(dtb, xz, xc, dbc, m1_A_log, m1_D, yb, 4096, 128);
  gemm(yb, 4096, m1_out_proj, 4096, mid, part, 2048, 4096, 8, 0, nullptr, stream);

  // ---------------- mamba block 2: DI=8192, DTR=256 ----------------
  gemm(mid, 2048, m2_in_proj, 2048, xz, part, 16384, 2048, 1, 0, nullptr, stream);
  k_conv_silu<<<(128 * 8192) / 256, 256, 0, stream>>>(xz, m2_conv_w, m2_conv_b, xc, 8192);
  gemm(xc, 8192, m2_x_proj, 8192, dbc, part, 384, 8192, 32, 0, nullptr, stream);
  gemm(dbc, 384, m2_dt_w, 256, dtb, part, 8192, 256, 2, 1, m2_dt_b, stream);
  k_scan<<<2048, 256, 0, stream>>>(dtb, xz, xc, dbc, m2_A_log, m2_D, yb, 8192, 256);
  gemm(yb, 8192, m2_out_proj, 8192, (float*)d_out, part, 4096, 8192, 4, 0, nullptr, stream);
}

// Round 2
// 668.699 us; speedup vs baseline: 5.8355x; 5.8355x over previous
//
#include <hip/hip_runtime.h>
#include <hip/hip_bf16.h>
#include <math.h>

// ---------------------------------------------------------------------------
// VaryMambaModel: batch=1, L=128
//   PRE_D=2048, D=4096, N=64, K=4, DI1=4096, DI2=8192, DTR1=128, DTR2=256
// f32 pipeline, round 1: occupancy-fixed 128x128-tile GEMM + split-K.
// ---------------------------------------------------------------------------

__device__ __forceinline__ float sigmoidf_(float x) {
  return 1.0f / (1.0f + __expf(-x));
}
__device__ __forceinline__ float softplusf_(float x) {
  return fmaxf(x, 0.0f) + log1pf(expf(-fabsf(x)));
}

// ---------------- prep: x0 = pe + cond*to_cond_w + to_cond_b ----------------
__global__ __launch_bounds__(256) void k_prep(const float* __restrict__ pe,
                                              const float* __restrict__ cw,
                                              const float* __restrict__ cb,
                                              const float* __restrict__ cond,
                                              float* __restrict__ x0) {
  int i = blockIdx.x * 256 + threadIdx.x;  // 128*2048
  int d = i & 2047;
  x0[i] = pe[i] + cond[0] * cw[d] + cb[d];
}

// ---------------- GEMM: P[s] += X[128xK] * W[NxK]^T, tile 128x128 -----------
// 256 threads, 8x8 micro-tile/thread, KC=32, split-K over blockIdx.z.
#define KC 32
__global__ __launch_bounds__(256, 3) void k_gemm(const float* __restrict__ X, int ldx,
                                                 const float* __restrict__ W, int ldw,
                                                 float* __restrict__ P,
                                                 int N, int Ks) {
  __shared__ float Xs[KC][132];
  __shared__ float Ws[KC][132];
  const int n0 = blockIdx.x * 128;
  const int s  = blockIdx.z;
  const int kbeg = s * Ks;
  const int t  = threadIdx.x;
  const int tx = t & 15;        // n-quads
  const int ty = t >> 4;        // m-quads

  float acc[8][8];
#pragma unroll
  for (int i = 0; i < 8; ++i)
#pragma unroll
    for (int j = 0; j < 8; ++j) acc[i][j] = 0.0f;

  const int mrow = t >> 3;          // 0..31
  const int kq4  = (t & 7) * 4;     // 0,4,...,28
  const float* Xp = X + (size_t)mrow * ldx + kbeg + kq4;
  const float* Wp = W + (size_t)(n0 + mrow) * ldw + kbeg + kq4;

  for (int k0 = 0; k0 < Ks; k0 += KC) {
    __syncthreads();
#pragma unroll
    for (int i = 0; i < 4; ++i) {
      const float4 xv = *(const float4*)(Xp + (size_t)(32 * i) * ldx + k0);
      const float4 wv = *(const float4*)(Wp + (size_t)(32 * i) * ldw + k0);
      const int m = mrow + 32 * i;
      Xs[kq4 + 0][m] = xv.x; Xs[kq4 + 1][m] = xv.y;
      Xs[kq4 + 2][m] = xv.z; Xs[kq4 + 3][m] = xv.w;
      Ws[kq4 + 0][m] = wv.x; Ws[kq4 + 1][m] = wv.y;
      Ws[kq4 + 2][m] = wv.z; Ws[kq4 + 3][m] = wv.w;
    }
    __syncthreads();
#pragma unroll
    for (int kk = 0; kk < KC; ++kk) {
      const float4 xa = *(const float4*)&Xs[kk][ty * 4];
      const float4 xb = *(const float4*)&Xs[kk][ty * 4 + 64];
      const float4 wa = *(const float4*)&Ws[kk][tx * 4];
      const float4 wb = *(const float4*)&Ws[kk][tx * 4 + 64];
      const float xr[8] = {xa.x, xa.y, xa.z, xa.w, xb.x, xb.y, xb.z, xb.w};
      const float wr[8] = {wa.x, wa.y, wa.z, wa.w, wb.x, wb.y, wb.z, wb.w};
#pragma unroll
      for (int i = 0; i < 8; ++i)
#pragma unroll
        for (int j = 0; j < 8; ++j) acc[i][j] = fmaf(xr[i], wr[j], acc[i][j]);
    }
  }

  float* Pd = P + (size_t)s * 128 * N + n0;
#pragma unroll
  for (int ih = 0; ih < 2; ++ih)
#pragma unroll
    for (int i = 0; i < 4; ++i) {
      const int m = ih * 64 + ty * 4 + i;
      float* row = Pd + (size_t)m * N;
      float4 v0 = make_float4(acc[ih*4+i][0], acc[ih*4+i][1], acc[ih*4+i][2], acc[ih*4+i][3]);
      float4 v1 = make_float4(acc[ih*4+i][4], acc[ih*4+i][5], acc[ih*4+i][6], acc[ih*4+i][7]);
      *(float4*)(row + tx * 4)      = v0;
      *(float4*)(row + tx * 4 + 64) = v1;
    }
}

// ---------------- reduce partials (+ optional softplus-bias epilogue) -------
__global__ __launch_bounds__(256) void k_reduce(const float* __restrict__ P,
                                                float* __restrict__ Y,
                                                int MN, int N, int S, int ep,
                                                const float* __restrict__ bias) {
  int i = (blockIdx.x * 256 + threadIdx.x) * 4;
  if (i >= MN) return;
  float4 v = *(const float4*)&P[i];
  for (int s = 1; s < S; ++s) {
    float4 p = *(const float4*)&P[(size_t)s * MN + i];
    v.x += p.x; v.y += p.y; v.z += p.z; v.w += p.w;
  }
  if (ep == 1) {
    int n = i % N;
    const float4 b = *(const float4*)&bias[n];
    v.x = softplusf_(v.x + b.x);
    v.y = softplusf_(v.y + b.y);
    v.z = softplusf_(v.z + b.z);
    v.w = softplusf_(v.w + b.w);
  }
  *(float4*)&Y[i] = v;
}

// stage-A reduce: sum groups of 8 partials (for S>16)
__global__ __launch_bounds__(256) void k_reduceA(const float* __restrict__ P,
                                                 float* __restrict__ Y, int MN) {
  int g = blockIdx.y;
  int i = (blockIdx.x * 256 + threadIdx.x) * 4;
  if (i >= MN) return;
  const float* Pp = P + (size_t)g * 8 * MN;
  float4 v = *(const float4*)&Pp[i];
  for (int s = 1; s < 8; ++s) {
    float4 p = *(const float4*)&Pp[(size_t)s * MN + i];
    v.x += p.x; v.y += p.y; v.z += p.z; v.w += p.w;
  }
  *(float4*)&Y[(size_t)g * MN + i] = v;
}

// ---------------- depthwise causal conv (K=4) + silu ------------------------
__global__ __launch_bounds__(256) void k_conv_silu(const float* __restrict__ xz,
                                                   const float* __restrict__ cw,
                                                   const float* __restrict__ cb,
                                                   float* __restrict__ xc, int DI) {
  int i = blockIdx.x * 256 + threadIdx.x;  // over 128*DI
  int l = i / DI;
  int d = i - l * DI;
  const float4 w = *(const float4*)&cw[d * 4];
  const float* xr = xz + d;
  int ld = 2 * DI;
  float s = cb[d];
  s += w.w * xr[l * ld];
  if (l >= 1) s += w.z * xr[(l - 1) * ld];
  if (l >= 2) s += w.y * xr[(l - 2) * ld];
  if (l >= 3) s += w.x * xr[(l - 3) * ld];
  xc[i] = s * sigmoidf_(s);
}

// ---------------- selective scan: wave per channel, lane = n ----------------
__global__ __launch_bounds__(256) void k_scan(const float* __restrict__ dt,
                                              const float* __restrict__ xz,
                                              const float* __restrict__ xc,
                                              const float* __restrict__ dbc,
                                              const float* __restrict__ A_log,
                                              const float* __restrict__ Dp,
                                              float* __restrict__ y,
                                              int DI, int DTR) {
  int d = blockIdx.x * 4 + (threadIdx.x >> 6);
  int lane = threadIdx.x & 63;
  float A = -__expf(A_log[d * 64 + lane]);
  float Dd = Dp[d];
  int ldbc = DTR + 128;
  const float* Bp = dbc + DTR + lane;
  const float* Cp = dbc + DTR + 64 + lane;
  float h = 0.0f;
  for (int l = 0; l < 128; ++l) {
    float dtv = dt[l * DI + d];
    float xcv = xc[l * DI + d];
    float zv  = xz[l * 2 * DI + DI + d];
    float Bv  = Bp[l * ldbc];
    float Cv  = Cp[l * ldbc];
    float dA  = __expf(dtv * A);
    h = dA * h + (dtv * Bv) * xcv;
    float c = h * Cv;
#pragma unroll
    for (int off = 32; off; off >>= 1) c += __shfl_xor(c, off, 64);
    if (lane == 0) y[l * DI + d] = (c + xcv * Dd) * (zv * sigmoidf_(zv));
  }
}

// ---------------------------------------------------------------------------
struct GemmCtx {
  float* part;
  float* part2;
  long long cap;  // floats available for `part`
};

static inline void gemm(const float* X, int ldx, const float* W, int ldw,
                        float* dst, int N, int K, int Sdes, int ep,
                        const float* bias, const GemmCtx& cx, hipStream_t stream) {
  int S = Sdes;
  if (S > K / KC) S = K / KC;
  if (S < 1) S = 1;
  while (S > 1 && (long long)S * 128 * N > cx.cap) S >>= 1;
  const int Ks = K / S;
  const bool direct = (S == 1 && ep == 0);
  dim3 g(N / 128, 1, S);
  k_gemm<<<g, 256, 0, stream>>>(X, ldx, W, ldw, direct ? dst : cx.part, N, Ks);
  if (direct) return;
  const int MN = 128 * N;
  const int rb = (MN / 4 + 255) / 256;
  if (S <= 16) {
    k_reduce<<<rb, 256, 0, stream>>>(cx.part, dst, MN, N, S, ep, bias);
  } else {
    k_reduceA<<<dim3(rb, S / 8), 256, 0, stream>>>(cx.part, cx.part2, MN);
    k_reduce<<<rb, 256, 0, stream>>>(cx.part2, dst, MN, N, S / 8, ep, bias);
  }
}

extern "C" void kernel_launch(void* const* d_in, const int* in_sizes, int n_in,
                              void* d_out, int out_size, void* d_ws, size_t ws_size,
                              hipStream_t stream) {
  const float* pe        = (const float*)d_in[0];
  const float* to_cond_w = (const float*)d_in[1];
  const float* to_cond_b = (const float*)d_in[2];
  const float* condition = (const float*)d_in[3];
  const int o = (in_sizes[4] == 1) ? 5 : 4;
  const float* m1_in_proj  = (const float*)d_in[o + 0];
  const float* m1_conv_w   = (const float*)d_in[o + 1];
  const float* m1_conv_b   = (const float*)d_in[o + 2];
  const float* m1_x_proj   = (const float*)d_in[o + 3];
  const float* m1_dt_w     = (const float*)d_in[o + 4];
  const float* m1_dt_b     = (const float*)d_in[o + 5];
  const float* m1_A_log    = (const float*)d_in[o + 6];
  const float* m1_D        = (const float*)d_in[o + 7];
  const float* m1_out_proj = (const float*)d_in[o + 8];
  const float* m2_in_proj  = (const float*)d_in[o + 9];
  const float* m2_conv_w   = (const float*)d_in[o + 10];
  const float* m2_conv_b   = (const float*)d_in[o + 11];
  const float* m2_x_proj   = (const float*)d_in[o + 12];
  const float* m2_dt_w     = (const float*)d_in[o + 13];
  const float* m2_dt_b     = (const float*)d_in[o + 14];
  const float* m2_A_log    = (const float*)d_in[o + 15];
  const float* m2_D        = (const float*)d_in[o + 16];
  const float* m2_out_proj = (const float*)d_in[o + 17];

  float* ws   = (float*)d_ws;
  float* x0   = ws;             // 262144
  float* mid  = ws + 262144;    // 262144
  float* xz   = ws + 524288;    // 2097152
  float* xc   = ws + 2621440;   // 1048576
  float* dbc  = ws + 3670016;   // 49152
  float* dtb  = ws + 3719168;   // 1048576
  float* yb   = ws + 4767744;   // 1048576
  float* part2= ws + 5816320;   // 524288 (2 MB)
  float* part = ws + 6340608;   // split-K partials (rest of ws)

  GemmCtx cx;
  cx.part = part;
  cx.part2 = part2;
  cx.cap = (long long)(ws_size / 4) - 6340608;
  if (cx.cap < 0) cx.cap = 0;

  k_prep<<<1024, 256, 0, stream>>>(pe, to_cond_w, to_cond_b, condition, x0);

  // ---------------- mamba block 1: DI=4096, DTR=128 ----------------
  gemm(x0, 2048, m1_in_proj, 2048, xz, 8192, 2048, 8, 0, nullptr, cx, stream);
  k_conv_silu<<<(128 * 4096) / 256, 256, 0, stream>>>(xz, m1_conv_w, m1_conv_b, xc, 4096);
  gemm(xc, 4096, m1_x_proj, 4096, dbc, 256, 4096, 128, 0, nullptr, cx, stream);
  gemm(dbc, 256, m1_dt_w, 128, dtb, 4096, 128, 4, 1, m1_dt_b, cx, stream);
  k_scan<<<1024, 256, 0, stream>>>(dtb, xz, xc, dbc, m1_A_log, m1_D, yb, 4096, 128);
  gemm(yb, 4096, m1_out_proj, 4096, mid, 2048, 4096, 32, 0, nullptr, cx, stream);

  // ---------------- mamba block 2: DI=8192, DTR=256 ----------------
  gemm(mid, 2048, m2_in_proj, 2048, xz, 16384, 2048, 4, 0, nullptr, cx, stream);
  k_conv_silu<<<(128 * 8192) / 256, 256, 0, stream>>>(xz, m2_conv_w, m2_conv_b, xc, 8192);
  gemm(xc, 8192, m2_x_proj, 8192, dbc, 384, 8192, 128, 0, nullptr, cx, stream);
  gemm(dbc, 384, m2_dt_w, 256, dtb, 8192, 256, 8, 1, m2_dt_b, cx, stream);
  k_scan<<<2048, 256, 0, stream>>>(dtb, xz, xc, dbc, m2_A_log, m2_D, yb, 8192, 256);
  gemm(yb, 8192, m2_out_proj, 8192, (float*)d_out, 4096, 8192, 16, 0, nullptr, cx, stream);
}

// Round 3
// 499.568 us; speedup vs baseline: 7.8112x; 1.3386x over previous
//
#include <hip/hip_runtime.h>
#include <hip/hip_bf16.h>
#include <math.h>

// ---------------------------------------------------------------------------
// VaryMambaModel: batch=1, L=128
//   PRE_D=2048, D=4096, N=64, K=4, DI1=4096, DI2=8192, DTR1=128, DTR2=256
// Round 2: GEMMs on MFMA (bf16 hi/lo split, 3-term) with fused f32->bf16x2
// conversion in the LDS staging step. Everything else f32.
// ---------------------------------------------------------------------------

typedef __attribute__((ext_vector_type(8))) short short8_t;   // 8 bf16 = 4 VGPR
typedef __attribute__((ext_vector_type(4))) float f32x4;      // MFMA C/D frag

__device__ __forceinline__ float sigmoidf_(float x) {
  return 1.0f / (1.0f + __expf(-x));
}
__device__ __forceinline__ float softplusf_(float x) {
  return fmaxf(x, 0.0f) + log1pf(expf(-fabsf(x)));
}

// ---------------- prep: x0 = pe + cond*to_cond_w + to_cond_b ----------------
__global__ __launch_bounds__(256) void k_prep(const float* __restrict__ pe,
                                              const float* __restrict__ cw,
                                              const float* __restrict__ cb,
                                              const float* __restrict__ cond,
                                              float* __restrict__ x0) {
  int i = blockIdx.x * 256 + threadIdx.x;  // 128*2048
  int d = i & 2047;
  x0[i] = pe[i] + cond[0] * cw[d] + cb[d];
}

// ---------------- MFMA GEMM: P[s] = X[128xKs] * W[NxKs]^T -------------------
// Tile 128(M) x 128(N), 256 threads = 4 waves (each wave: 128m x 32n).
// K-step 32 f32. f32 operands are split to bf16 hi/lo in staging; inner loop
// does 3 MFMA terms (hh, hl, lh) per fragment with mfma_f32_16x16x32_bf16.
#define KSTEP 32
__global__ __launch_bounds__(256, 3) void k_gemm(const float* __restrict__ X, int ldx,
                                                 const float* __restrict__ W, int ldw,
                                                 float* __restrict__ P,
                                                 int N, int Ks) {
  // fragment-ordered LDS: [kb][row][8 bf16] ; frag read = 1x ds_read_b128
  __shared__ ushort Ah[4][128][8];
  __shared__ ushort Al[4][128][8];
  __shared__ ushort Bh[4][128][8];
  __shared__ ushort Bl[4][128][8];

  const int n0   = blockIdx.x * 128;
  const int s    = blockIdx.z;
  const int kbeg = s * Ks;
  const int t    = threadIdx.x;
  const int l    = t & 63;
  const int w    = t >> 6;      // wave id: n-subtile 32*w
  const int lr   = l & 15;
  const int lg   = l >> 4;

  f32x4 acc[8][2];
#pragma unroll
  for (int mi = 0; mi < 8; ++mi)
#pragma unroll
    for (int ni = 0; ni < 2; ++ni) acc[mi][ni] = (f32x4)(0.0f);

  for (int k0 = kbeg; k0 < kbeg + Ks; k0 += KSTEP) {
    __syncthreads();
    // ---- stage: 128x32 f32 of X and of W -> bf16 hi/lo in LDS ----
    float4 va[4], vb[4];
#pragma unroll
    for (int i = 0; i < 4; ++i) {
      const int c4  = lg + 4 * (i & 1);              // which float4 along k
      const int row = lr + 16 * (i >> 1) + 32 * w;   // tile row
      va[i] = *(const float4*)(X + (size_t)row * ldx + k0 + 4 * c4);
      vb[i] = *(const float4*)(W + (size_t)(n0 + row) * ldw + k0 + 4 * c4);
    }
#pragma unroll
    for (int i = 0; i < 4; ++i) {
      const int c4  = lg + 4 * (i & 1);
      const int row = lr + 16 * (i >> 1) + 32 * w;
      const int kb  = c4 >> 1;
      const int eo  = (c4 & 1) * 4;
      const float xa[4] = {va[i].x, va[i].y, va[i].z, va[i].w};
      const float xb[4] = {vb[i].x, vb[i].y, vb[i].z, vb[i].w};
      ushort4 ha, la, hb, lb;
      ushort* hap = (ushort*)&ha; ushort* lap = (ushort*)&la;
      ushort* hbp = (ushort*)&hb; ushort* lbp = (ushort*)&lb;
#pragma unroll
      for (int j = 0; j < 4; ++j) {
        __hip_bfloat16 h = __float2bfloat16(xa[j]);
        hap[j] = *reinterpret_cast<ushort*>(&h);
        __hip_bfloat16 lo = __float2bfloat16(xa[j] - __bfloat162float(h));
        lap[j] = *reinterpret_cast<ushort*>(&lo);
        __hip_bfloat16 h2 = __float2bfloat16(xb[j]);
        hbp[j] = *reinterpret_cast<ushort*>(&h2);
        __hip_bfloat16 lo2 = __float2bfloat16(xb[j] - __bfloat162float(h2));
        lbp[j] = *reinterpret_cast<ushort*>(&lo2);
      }
      *(ushort4*)&Ah[kb][row][eo] = ha;
      *(ushort4*)&Al[kb][row][eo] = la;
      *(ushort4*)&Bh[kb][row][eo] = hb;
      *(ushort4*)&Bl[kb][row][eo] = lb;
    }
    __syncthreads();

    // ---- compute ----
    const short8_t bh0 = *(const short8_t*)&Bh[lg][32 * w + lr][0];
    const short8_t bl0 = *(const short8_t*)&Bl[lg][32 * w + lr][0];
    const short8_t bh1 = *(const short8_t*)&Bh[lg][32 * w + 16 + lr][0];
    const short8_t bl1 = *(const short8_t*)&Bl[lg][32 * w + 16 + lr][0];
#pragma unroll
    for (int mi = 0; mi < 8; ++mi) {
      const short8_t ah = *(const short8_t*)&Ah[lg][16 * mi + lr][0];
      const short8_t al = *(const short8_t*)&Al[lg][16 * mi + lr][0];
      acc[mi][0] = __builtin_amdgcn_mfma_f32_16x16x32_bf16(ah, bh0, acc[mi][0], 0, 0, 0);
      acc[mi][1] = __builtin_amdgcn_mfma_f32_16x16x32_bf16(ah, bh1, acc[mi][1], 0, 0, 0);
      acc[mi][0] = __builtin_amdgcn_mfma_f32_16x16x32_bf16(ah, bl0, acc[mi][0], 0, 0, 0);
      acc[mi][1] = __builtin_amdgcn_mfma_f32_16x16x32_bf16(ah, bl1, acc[mi][1], 0, 0, 0);
      acc[mi][0] = __builtin_amdgcn_mfma_f32_16x16x32_bf16(al, bh0, acc[mi][0], 0, 0, 0);
      acc[mi][1] = __builtin_amdgcn_mfma_f32_16x16x32_bf16(al, bh1, acc[mi][1], 0, 0, 0);
    }
  }

  // ---- epilogue: C/D layout col=lane&15, row=4*(lane>>4)+j (m89) ----
  float* Pd = P + (size_t)s * 128 * N + n0;
#pragma unroll
  for (int mi = 0; mi < 8; ++mi)
#pragma unroll
    for (int ni = 0; ni < 2; ++ni) {
#pragma unroll
      for (int j = 0; j < 4; ++j) {
        const int m = 16 * mi + 4 * lg + j;
        Pd[(size_t)m * N + 32 * w + 16 * ni + lr] = acc[mi][ni][j];
      }
    }
}

// ---------------- reduce partials (+ optional softplus-bias epilogue) -------
__global__ __launch_bounds__(256) void k_reduce(const float* __restrict__ P,
                                                float* __restrict__ Y,
                                                int MN, int N, int S, int ep,
                                                const float* __restrict__ bias) {
  int i = (blockIdx.x * 256 + threadIdx.x) * 4;
  if (i >= MN) return;
  float4 v = *(const float4*)&P[i];
  for (int s = 1; s < S; ++s) {
    float4 p = *(const float4*)&P[(size_t)s * MN + i];
    v.x += p.x; v.y += p.y; v.z += p.z; v.w += p.w;
  }
  if (ep == 1) {
    int n = i % N;
    const float4 b = *(const float4*)&bias[n];
    v.x = softplusf_(v.x + b.x);
    v.y = softplusf_(v.y + b.y);
    v.z = softplusf_(v.z + b.z);
    v.w = softplusf_(v.w + b.w);
  }
  *(float4*)&Y[i] = v;
}

// stage-A reduce: sum groups of 8 partials (for S>16)
__global__ __launch_bounds__(256) void k_reduceA(const float* __restrict__ P,
                                                 float* __restrict__ Y, int MN) {
  int g = blockIdx.y;
  int i = (blockIdx.x * 256 + threadIdx.x) * 4;
  if (i >= MN) return;
  const float* Pp = P + (size_t)g * 8 * MN;
  float4 v = *(const float4*)&Pp[i];
  for (int s = 1; s < 8; ++s) {
    float4 p = *(const float4*)&Pp[(size_t)s * MN + i];
    v.x += p.x; v.y += p.y; v.z += p.z; v.w += p.w;
  }
  *(float4*)&Y[(size_t)g * MN + i] = v;
}

// ---------------- depthwise causal conv (K=4) + silu ------------------------
__global__ __launch_bounds__(256) void k_conv_silu(const float* __restrict__ xz,
                                                   const float* __restrict__ cw,
                                                   const float* __restrict__ cb,
                                                   float* __restrict__ xc, int DI) {
  int i = blockIdx.x * 256 + threadIdx.x;  // over 128*DI
  int l = i / DI;
  int d = i - l * DI;
  const float4 w = *(const float4*)&cw[d * 4];
  const float* xr = xz + d;
  int ld = 2 * DI;
  float s = cb[d];
  s += w.w * xr[l * ld];
  if (l >= 1) s += w.z * xr[(l - 1) * ld];
  if (l >= 2) s += w.y * xr[(l - 2) * ld];
  if (l >= 3) s += w.x * xr[(l - 3) * ld];
  xc[i] = s * sigmoidf_(s);
}

// ---------------- selective scan: wave per channel, lane = n ----------------
__global__ __launch_bounds__(256) void k_scan(const float* __restrict__ dt,
                                              const float* __restrict__ xz,
                                              const float* __restrict__ xc,
                                              const float* __restrict__ dbc,
                                              const float* __restrict__ A_log,
                                              const float* __restrict__ Dp,
                                              float* __restrict__ y,
                                              int DI, int DTR) {
  int d = blockIdx.x * 4 + (threadIdx.x >> 6);
  int lane = threadIdx.x & 63;
  float A = -__expf(A_log[d * 64 + lane]);
  float Dd = Dp[d];
  int ldbc = DTR + 128;
  const float* Bp = dbc + DTR + lane;
  const float* Cp = dbc + DTR + 64 + lane;
  float h = 0.0f;
  for (int l = 0; l < 128; ++l) {
    float dtv = dt[l * DI + d];
    float xcv = xc[l * DI + d];
    float zv  = xz[l * 2 * DI + DI + d];
    float Bv  = Bp[l * ldbc];
    float Cv  = Cp[l * ldbc];
    float dA  = __expf(dtv * A);
    h = dA * h + (dtv * Bv) * xcv;
    float c = h * Cv;
#pragma unroll
    for (int off = 32; off; off >>= 1) c += __shfl_xor(c, off, 64);
    if (lane == 0) y[l * DI + d] = (c + xcv * Dd) * (zv * sigmoidf_(zv));
  }
}

// ---------------------------------------------------------------------------
struct GemmCtx {
  float* part;
  float* part2;
  long long cap;  // floats available for `part`
};

static inline void gemm(const float* X, int ldx, const float* W, int ldw,
                        float* dst, int N, int K, int Sdes, int ep,
                        const float* bias, const GemmCtx& cx, hipStream_t stream) {
  int S = Sdes;
  if (S > K / KSTEP) S = K / KSTEP;
  if (S < 1) S = 1;
  while (S > 1 && (long long)S * 128 * N > cx.cap) S >>= 1;
  const int Ks = K / S;
  const bool direct = (S == 1 && ep == 0);
  dim3 g(N / 128, 1, S);
  k_gemm<<<g, 256, 0, stream>>>(X, ldx, W, ldw, direct ? dst : cx.part, N, Ks);
  if (direct) return;
  const int MN = 128 * N;
  const int rb = (MN / 4 + 255) / 256;
  if (S <= 16) {
    k_reduce<<<rb, 256, 0, stream>>>(cx.part, dst, MN, N, S, ep, bias);
  } else {
    k_reduceA<<<dim3(rb, S / 8), 256, 0, stream>>>(cx.part, cx.part2, MN);
    k_reduce<<<rb, 256, 0, stream>>>(cx.part2, dst, MN, N, S / 8, ep, bias);
  }
}

extern "C" void kernel_launch(void* const* d_in, const int* in_sizes, int n_in,
                              void* d_out, int out_size, void* d_ws, size_t ws_size,
                              hipStream_t stream) {
  const float* pe        = (const float*)d_in[0];
  const float* to_cond_w = (const float*)d_in[1];
  const float* to_cond_b = (const float*)d_in[2];
  const float* condition = (const float*)d_in[3];
  const int o = (in_sizes[4] == 1) ? 5 : 4;
  const float* m1_in_proj  = (const float*)d_in[o + 0];
  const float* m1_conv_w   = (const float*)d_in[o + 1];
  const float* m1_conv_b   = (const float*)d_in[o + 2];
  const float* m1_x_proj   = (const float*)d_in[o + 3];
  const float* m1_dt_w     = (const float*)d_in[o + 4];
  const float* m1_dt_b     = (const float*)d_in[o + 5];
  const float* m1_A_log    = (const float*)d_in[o + 6];
  const float* m1_D        = (const float*)d_in[o + 7];
  const float* m1_out_proj = (const float*)d_in[o + 8];
  const float* m2_in_proj  = (const float*)d_in[o + 9];
  const float* m2_conv_w   = (const float*)d_in[o + 10];
  const float* m2_conv_b   = (const float*)d_in[o + 11];
  const float* m2_x_proj   = (const float*)d_in[o + 12];
  const float* m2_dt_w     = (const float*)d_in[o + 13];
  const float* m2_dt_b     = (const float*)d_in[o + 14];
  const float* m2_A_log    = (const float*)d_in[o + 15];
  const float* m2_D        = (const float*)d_in[o + 16];
  const float* m2_out_proj = (const float*)d_in[o + 17];

  float* ws   = (float*)d_ws;
  float* x0   = ws;             // 262144
  float* mid  = ws + 262144;    // 262144
  float* xz   = ws + 524288;    // 2097152
  float* xc   = ws + 2621440;   // 1048576
  float* dbc  = ws + 3670016;   // 49152
  float* dtb  = ws + 3719168;   // 1048576
  float* yb   = ws + 4767744;   // 1048576
  float* part2= ws + 5816320;   // 524288 (2 MB)
  float* part = ws + 6340608;   // split-K partials (rest of ws)

  GemmCtx cx;
  cx.part = part;
  cx.part2 = part2;
  cx.cap = (long long)(ws_size / 4) - 6340608;
  if (cx.cap < 0) cx.cap = 0;

  k_prep<<<1024, 256, 0, stream>>>(pe, to_cond_w, to_cond_b, condition, x0);

  // ---------------- mamba block 1: DI=4096, DTR=128 ----------------
  gemm(x0, 2048, m1_in_proj, 2048, xz, 8192, 2048, 8, 0, nullptr, cx, stream);
  k_conv_silu<<<(128 * 4096) / 256, 256, 0, stream>>>(xz, m1_conv_w, m1_conv_b, xc, 4096);
  gemm(xc, 4096, m1_x_proj, 4096, dbc, 256, 4096, 128, 0, nullptr, cx, stream);
  gemm(dbc, 256, m1_dt_w, 128, dtb, 4096, 128, 4, 1, m1_dt_b, cx, stream);
  k_scan<<<1024, 256, 0, stream>>>(dtb, xz, xc, dbc, m1_A_log, m1_D, yb, 4096, 128);
  gemm(yb, 4096, m1_out_proj, 4096, mid, 2048, 4096, 32, 0, nullptr, cx, stream);

  // ---------------- mamba block 2: DI=8192, DTR=256 ----------------
  gemm(mid, 2048, m2_in_proj, 2048, xz, 16384, 2048, 4, 0, nullptr, cx, stream);
  k_conv_silu<<<(128 * 8192) / 256, 256, 0, stream>>>(xz, m2_conv_w, m2_conv_b, xc, 8192);
  gemm(xc, 8192, m2_x_proj, 8192, dbc, 384, 8192, 128, 0, nullptr, cx, stream);
  gemm(dbc, 384, m2_dt_w, 256, dtb, 8192, 256, 8, 1, m2_dt_b, cx, stream);
  k_scan<<<2048, 256, 0, stream>>>(dtb, xz, xc, dbc, m2_A_log, m2_D, yb, 8192, 256);
  gemm(yb, 8192, m2_out_proj, 8192, (float*)d_out, 4096, 8192, 16, 0, nullptr, cx, stream);
}